// Round 1
// baseline (58.658 us; speedup 1.0000x reference)
//
#include <hip/hip_runtime.h>
#include <math.h>

// One 256-thread block per walker b. S=2, N=8, D=256, I=4.
// Phases: stage(h,W^T,r,dec,pi) -> dist + lin-partials -> env*lin=M ->
//         16 per-thread 7x7 dets (cofactor col 0) -> out = h * anti.

__global__ __launch_bounds__(256, 4)
void orbital_cof_kernel(const float* __restrict__ h_g,   // (B,16,256)
                        const float* __restrict__ r_g,   // (B,16,4,3)
                        const float* __restrict__ W_g,   // (2,256,8)
                        const float* __restrict__ b_g,   // (2,8)
                        const float* __restrict__ dec_g, // (2,4,8)
                        const float* __restrict__ pi_g,  // (2,4,8)
                        float* __restrict__ out,         // (2,B,8,256)
                        int nb)
{
    __shared__ float hs[16][260];   // h rows, padded stride (16B-aligned, bank-spread)
    __shared__ float Wt[16][260];   // W transposed: [s*8+k][d]
    __shared__ float partial[256];
    __shared__ float Ms[2][8][8];
    __shared__ float anti_s[16];
    __shared__ float dist_s[64];    // [s*32 + n*4 + i]
    __shared__ float rs[192];
    __shared__ float dec_s[64];
    __shared__ float pi_s[64];

    const int t = threadIdx.x;
    const int b = blockIdx.x;

    // ---- stage h (1024 float4, coalesced) ----
    const float4* h4 = (const float4*)(h_g + (size_t)b * 4096);
#pragma unroll
    for (int it = 0; it < 4; ++it) {
        int f4 = t + it * 256;          // 0..1023
        int row = f4 >> 6;              // s*8+n
        int d4 = (f4 & 63) << 2;
        float4 v = h4[f4];
        *(float4*)&hs[row][d4] = v;
    }
    // ---- stage W transposed (coalesced read, scattered 2-way-conflict writes) ----
    const float4* w4 = (const float4*)W_g;
#pragma unroll
    for (int it = 0; it < 4; ++it) {
        int f4 = t + it * 256;          // flat = f4*4 = s*2048 + d*8 + k
        int flat = f4 << 2;
        int s = flat >> 11;
        int d = (flat >> 3) & 255;
        int k0 = flat & 7;
        float4 v = w4[f4];
        Wt[s * 8 + k0 + 0][d] = v.x;
        Wt[s * 8 + k0 + 1][d] = v.y;
        Wt[s * 8 + k0 + 2][d] = v.z;
        Wt[s * 8 + k0 + 3][d] = v.w;
    }
    // ---- stage r + params ----
    if (t < 192) {
        rs[t] = r_g[(size_t)b * 192 + t];
    } else {
        int u = t - 192;
        if (u < 64) { dec_s[u] = dec_g[u]; pi_s[u] = pi_g[u]; }
    }
    __syncthreads();

    // ---- distances (wave 0) ----
    if (t < 64) {   // t = s*32 + n*4 + i  (matches r flat/3 layout)
        float x = rs[t * 3], y = rs[t * 3 + 1], z = rs[t * 3 + 2];
        dist_s[t] = sqrtf(x * x + y * y + z * z);
    }

    // ---- lin partial dot products: o=(s,n,k), half of K each ----
    {
        int o = t & 127;
        int half = t >> 7;
        int sn = o >> 3;                // s*8+n
        int k = o & 7;
        int s = sn >> 3;
        const float* hrow = &hs[sn][half * 128];
        const float* wrow = &Wt[s * 8 + k][half * 128];
        float acc = 0.f;
#pragma unroll
        for (int d = 0; d < 128; d += 4) {
            float4 hv = *(const float4*)&hrow[d];
            float4 wv = *(const float4*)&wrow[d];
            acc = fmaf(hv.x, wv.x, acc);
            acc = fmaf(hv.y, wv.y, acc);
            acc = fmaf(hv.z, wv.z, acc);
            acc = fmaf(hv.w, wv.w, acc);
        }
        partial[t] = acc;
    }
    __syncthreads();

    // ---- combine + envelope -> orbital matrix M ----
    if (t < 128) {
        int s = t >> 6;
        int n = (t >> 3) & 7;
        int k = t & 7;
        float lin = partial[t] + partial[t + 128] + b_g[s * 8 + k];
        float env = 0.f;
#pragma unroll
        for (int i = 0; i < 4; ++i) {
            float dd = dist_s[s * 32 + n * 4 + i];
            env = fmaf(pi_s[s * 32 + i * 8 + k], __expf(-dd * dec_s[s * 32 + i * 8 + k]), env);
        }
        Ms[s][n][k] = lin * env;
    }
    __syncthreads();

    // ---- 16 cofactor determinants (7x7, partial pivoting, all reg-resident) ----
    if (t < 16) {
        int s = t >> 3;
        int n = t & 7;
        float a[7][7];
#pragma unroll
        for (int i = 0; i < 7; ++i) {
            int src = i + (i >= n);     // skip row n
#pragma unroll
            for (int j = 0; j < 7; ++j) a[i][j] = Ms[s][src][j + 1];  // skip col 0
        }
        float det = 1.f;
#pragma unroll
        for (int kk = 0; kk < 7; ++kk) {
            // bubble max-|pivot| into row kk (compile-time indices only)
#pragma unroll
            for (int i = kk + 1; i < 7; ++i) {
                bool sw = fabsf(a[i][kk]) > fabsf(a[kk][kk]);
#pragma unroll
                for (int j = kk; j < 7; ++j) {
                    float tk = a[kk][j], ti = a[i][j];
                    a[kk][j] = sw ? ti : tk;
                    a[i][j]  = sw ? tk : ti;
                }
                det = sw ? -det : det;
            }
            float piv = a[kk][kk];
            det *= piv;
            float rp = (piv != 0.f) ? (1.f / piv) : 0.f;  // piv==0 => det=0, keep NaN out
#pragma unroll
            for (int i = kk + 1; i < 7; ++i) {
                float f = a[i][kk] * rp;
#pragma unroll
                for (int j = kk + 1; j < 7; ++j) a[i][j] = fmaf(-f, a[kk][j], a[i][j]);
            }
        }
        float sgn = (n & 1) ? -1.f : 1.f;
        anti_s[t] = Ms[s][n][0] * sgn * det;
    }
    __syncthreads();

    // ---- out = h * anti, coalesced float4 stores; tuple layout (s=0 block, s=1 block)
#pragma unroll
    for (int it = 0; it < 4; ++it) {
        int f4 = t + it * 256;
        int row = f4 >> 6;              // s*8+n
        int d4 = (f4 & 63) << 2;
        float4 v = *(const float4*)&hs[row][d4];
        float aa = anti_s[row];
        float4 o = make_float4(v.x * aa, v.y * aa, v.z * aa, v.w * aa);
        int s = row >> 3;
        int n = row & 7;
        size_t off = (size_t)s * (size_t)nb * 2048 + (size_t)b * 2048 + (size_t)(n * 256 + d4);
        *(float4*)(out + off) = o;
    }
}

extern "C" void kernel_launch(void* const* d_in, const int* in_sizes, int n_in,
                              void* d_out, int out_size, void* d_ws, size_t ws_size,
                              hipStream_t stream) {
    int nb = in_sizes[0] / 4096;        // B = elems / (S*N*D)
    const float* h_g   = (const float*)d_in[0];
    const float* r_g   = (const float*)d_in[1];
    const float* W_g   = (const float*)d_in[2];
    const float* b_g   = (const float*)d_in[3];
    const float* dec_g = (const float*)d_in[4];
    const float* pi_g  = (const float*)d_in[5];
    orbital_cof_kernel<<<dim3(nb), dim3(256), 0, stream>>>(
        h_g, r_g, W_g, b_g, dec_g, pi_g, (float*)d_out, nb);
}